// Round 9
// baseline (169.986 us; speedup 1.0000x reference)
//
#include <hip/hip_runtime.h>
#include <cstdint>
#include <cstddef>

// Problem constants
#define BB 8
#define TT 1024
#define CC 768
#define NH 12
#define HD 64
// GEMM1: M=8192 N=2304 K=768.  GEMM2: M=8192 N=768 K=768.

using bf16x8 = __attribute__((ext_vector_type(8))) short;  // 8 bf16 (4 VGPRs)
using f32x4  = __attribute__((ext_vector_type(4))) float;  // 4 fp32

static __device__ __forceinline__ short f2bf(float f) {
    uint32_t u;
    __builtin_memcpy(&u, &f, 4);
    u += 0x7FFFu + ((u >> 16) & 1u);   // RNE
    return (short)(u >> 16);
}

static __device__ __forceinline__ uint32_t bfpack(float lo, float hi) {
    return (uint32_t)(uint16_t)f2bf(lo) | ((uint32_t)(uint16_t)f2bf(hi) << 16);
}

#define GLOAD_LDS16(gp, lp)                                                        \
    __builtin_amdgcn_global_load_lds(                                              \
        (const __attribute__((address_space(1))) void*)(gp),                       \
        (__attribute__((address_space(3))) void*)(lp), 16, 0, 0)

// ---------------------------------------------------------------- fc table
__global__ void fc_kernel(float2* __restrict__ fc) {
    int idx = blockIdx.x * 256 + threadIdx.x;   // 32768 = 1024*32
    int t = idx >> 5, p = idx & 31;
    float freq = powf(10000.0f, -(float)p / 32.0f);
    float a = (float)t * freq;
    fc[idx] = make_float2(cosf(a), sinf(a));
}

// ---------------------------------------------------------------- x fp32 -> bf16
__global__ __launch_bounds__(256)
void cast_kernel(const float* __restrict__ in, short* __restrict__ out) {
    int i = (blockIdx.x * 256 + threadIdx.x) * 8;
    float4 f0 = *(const float4*)(in + i);
    float4 f1 = *(const float4*)(in + i + 4);
    bf16x8 h;
    h[0] = f2bf(f0.x); h[1] = f2bf(f0.y); h[2] = f2bf(f0.z); h[3] = f2bf(f0.w);
    h[4] = f2bf(f1.x); h[5] = f2bf(f1.y); h[6] = f2bf(f1.z); h[7] = f2bf(f1.w);
    *(bf16x8*)(out + i) = h;
}

// ------------------------------------------- transpose fp32 [R][C] -> bf16 [C][R]
__global__ __launch_bounds__(256)
void transpose_cast_kernel(const float* __restrict__ in, short* __restrict__ out,
                           int R, int Cdim) {
    __shared__ float tile[32][33];
    int tx = threadIdx.x, ty = threadIdx.y;
    int c0 = blockIdx.x * 32, r0 = blockIdx.y * 32;
#pragma unroll
    for (int i = 0; i < 4; i++)
        tile[ty + 8 * i][tx] = in[(size_t)(r0 + ty + 8 * i) * Cdim + c0 + tx];
    __syncthreads();
#pragma unroll
    for (int i = 0; i < 4; i++)
        out[(size_t)(c0 + ty + 8 * i) * R + r0 + tx] = f2bf(tile[tx][ty + 8 * i]);
}

// ------------------------------------------- V [bh][t][64] -> VT [bh][64][t] (bf16)
__global__ __launch_bounds__(256)
void vtrans_kernel(const short* __restrict__ V, short* __restrict__ VT) {
    __shared__ short tl[64][72];
    const int tid = threadIdx.x;
    const int bh = blockIdx.y, t0 = blockIdx.x * 64;
    {
        int r = tid >> 2, cs = (tid & 3) * 16;
        const short* src = V + (size_t)bh * TT * HD + (size_t)(t0 + r) * HD + cs;
        *(bf16x8*)&tl[r][cs]     = *(const bf16x8*)src;
        *(bf16x8*)&tl[r][cs + 8] = *(const bf16x8*)(src + 8);
    }
    __syncthreads();
    {
        int d = tid >> 2, ts = (tid & 3) * 16;
        bf16x8 o0, o1;
#pragma unroll
        for (int e = 0; e < 8; e++) { o0[e] = tl[ts + e][d]; o1[e] = tl[ts + 8 + e][d]; }
        short* dst = VT + (size_t)bh * TT * HD + (size_t)d * TT + t0 + ts;
        *(bf16x8*)dst       = o0;
        *(bf16x8*)(dst + 8) = o1;
    }
}

// ---------------------------------------------------------------- pipelined GEMM
// r9 = r8 with the prologue arg-transposition bug fixed: second prologue stage
// must be slot1 <- (tile0, kh1) i.e. STAGE(1, 0, 1); r8 had STAGE(0, 1, 1) which
// double-staged slot0 and left slot1 uninitialized (NaN source).
// Rolling 3-slot kh pipeline, 48 KB LDS -> 3 blocks/CU, ONE barrier + ONE
// vmcnt(4) per phase. Phase p reads slot p%3, stages (tile+1, kh=p&1) into slot
// (p+2)%3. Hazards: read slot staged 2 phases earlier (retired by prior phase's
// vmcnt(4), published by its barrier); staged slot last read 1 phase earlier
// (reads complete before that wave's barrier via compiler lgkmcnt before MFMA).
// End-of-kernel vmcnt(0) drain for BOTH EPI paths (r6 race fix).
template <int EPI>
__global__ __launch_bounds__(256)
void gemm_kernel(const short* __restrict__ Agl, const short* __restrict__ BT,
                 const float* __restrict__ bias,
                 short* __restrict__ Qb, short* __restrict__ Kb, short* __restrict__ Vb,
                 const float2* __restrict__ fc, float* __restrict__ out) {
    __shared__ __align__(16) char smem[49152];   // 48 KB = 3 slots x 16 KB (A 8K | B 8K)
    const int tid = threadIdx.x;
    const int lane = tid & 63, wid = tid >> 6;
    const int g = lane >> 4, c = lane & 15;
    const int wm = wid >> 1, wn = wid & 1;       // 2 x 2 wave grid

    // bijective XCD swizzle (nwg % 8 == 0: 1152 and 384)
    const int nx = gridDim.x;
    const int bid = blockIdx.y * nx + blockIdx.x;
    const int cpx = (nx * gridDim.y) >> 3;
    const int swz = (bid & 7) * cpx + (bid >> 3);
    const int m0 = (swz / nx) * 128, n0 = (swz % nx) * 128;

    // staging mapping: instruction (matrix, q) covers rows wid*32+q*16+(lane>>2),
    // 16B col-chunk (lane&3), with XOR source-swizzle (chunk ^ ((row>>1)&3)).
    const int sr = lane >> 2;                       // 0..15
    const int scol = (((lane & 3) ^ ((sr >> 1) & 3)) << 3);  // bf16 col in 32
    const short* Abase = Agl + (size_t)(m0 + wid * 32 + sr) * 768 + scol;
    const short* Bbase = BT  + (size_t)(n0 + wid * 32 + sr) * 768 + scol;

    // slot S (16 KB): A kh-tile [128][32] @ S*16384, B kh-tile @ S*16384+8192.
#define STAGE(S, T, KH)                                                          \
    {                                                                            \
        size_t ko = (size_t)(T) * 64 + (KH) * 32;                                \
        GLOAD_LDS16(Abase + ko,            smem + (S) * 16384 + wid * 2048);     \
        GLOAD_LDS16(Abase + 16 * 768 + ko, smem + (S) * 16384 + wid * 2048 + 1024); \
        GLOAD_LDS16(Bbase + ko,            smem + (S) * 16384 + 8192 + wid * 2048); \
        GLOAD_LDS16(Bbase + 16 * 768 + ko, smem + (S) * 16384 + 8192 + wid * 2048 + 1024); \
    }

    const f32x4 zero4 = {0.f, 0.f, 0.f, 0.f};
    f32x4 acc[4][4];
#pragma unroll
    for (int i = 0; i < 4; i++)
#pragma unroll
        for (int j = 0; j < 4; j++) acc[i][j] = zero4;

    // prologue: slot0 <- (tile0,kh0), slot1 <- (tile0,kh1); wait slot0 landed
    STAGE(0, 0, 0);
    STAGE(1, 0, 1);
    asm volatile("s_waitcnt vmcnt(4)" ::: "memory");
    asm volatile("s_barrier" ::: "memory");

    // 24 phases; slot pattern period 3 -> unroll 6 phases (3 tiles) per group
    for (int t3 = 0; t3 < 12; t3 += 3) {
#pragma unroll
        for (int pp = 0; pp < 6; pp++) {
            const int slotR = pp % 3;
            const int slotS = (pp + 2) % 3;
            const int tile = t3 + (pp >> 1);
            const int kk = pp & 1;
            int tileS = tile + 1;
            if (tileS >= 12) tileS -= 12;   // wrap stage: never read, drained below

            const short* Ab = (const short*)(smem + slotR * 16384);
            const short* Bb = (const short*)(smem + slotR * 16384 + 8192);
            bf16x8 af[4], bfr[4];
#pragma unroll
            for (int mi = 0; mi < 4; mi++) {
                int row = wm * 64 + mi * 16 + c;
                af[mi] = *(const bf16x8*)&Ab[row * 32 + ((g ^ ((row >> 1) & 3)) << 3)];
            }
#pragma unroll
            for (int ni = 0; ni < 4; ni++) {
                int row = wn * 64 + ni * 16 + c;
                bfr[ni] = *(const bf16x8*)&Bb[row * 32 + ((g ^ ((row >> 1) & 3)) << 3)];
            }
            STAGE(slotS, tileS, kk);
            __builtin_amdgcn_s_setprio(1);
#pragma unroll
            for (int mi = 0; mi < 4; mi++)
#pragma unroll
                for (int ni = 0; ni < 4; ni++)
                    acc[mi][ni] = __builtin_amdgcn_mfma_f32_16x16x32_bf16(
                        af[mi], bfr[ni], acc[mi][ni], 0, 0, 0);
            __builtin_amdgcn_s_setprio(0);
            asm volatile("s_waitcnt vmcnt(4)" ::: "memory");
            asm volatile("s_barrier" ::: "memory");
        }
    }

    // Drain ALL outstanding global_load_lds DMAs before the epilogue / endpgm,
    // BOTH EPI paths (r6 race fix: in-flight DMA from a finished block corrupts
    // the next block's LDS in the same CU slot).
    asm volatile("s_waitcnt vmcnt(0)" ::: "memory");
    asm volatile("s_barrier" ::: "memory");

    if (EPI == 0) {
        // Phase 1: RoPE on (even,odd) col pairs -> swizzled LDS [128][64 words]
        uint32_t* LD = (uint32_t*)smem;   // 32 KB (fits in 48)
#pragma unroll
        for (int ni = 0; ni < 4; ni++) {
            int nl = wn * 64 + ni * 16 + c;
            int n = n0 + nl;
            float bv = bias[n];
            int part = (n >= 1536) ? 2 : (n >= 768 ? 1 : 0);
            int d = (n - part * 768) & 63;
#pragma unroll
            for (int mi = 0; mi < 4; mi++) {
#pragma unroll
                for (int r = 0; r < 4; r++) {
                    int ml = wm * 64 + mi * 16 + g * 4 + r;
                    float v = acc[mi][ni][r] + bv;
                    float pv = __shfl_xor(v, 1);   // partner col n^1 (all lanes exec)
                    if (!(c & 1)) {
                        float o0, o1;
                        if (part < 2) {
                            int t = (m0 + ml) & 1023;
                            float2 cs = fc[t * 32 + (d >> 1)];
                            o0 = v * cs.x - pv * cs.y;
                            o1 = v * cs.y + pv * cs.x;
                            if (part == 0) { o0 *= 0.125f; o1 *= 0.125f; }
                        } else { o0 = v; o1 = pv; }
                        LD[ml * 64 + ((nl >> 1) ^ (((ml >> 2) & 3) << 3))] = bfpack(o0, o1);
                    }
                }
            }
        }
        __syncthreads();
        // Phase 2: coalesced 16B scatter stores.
#pragma unroll
        for (int p = 0; p < 8; p++) {
            int ml = p * 16 + (tid >> 4);
            int wc = (tid & 15) * 4;
            int4 dat = *(const int4*)&LD[ml * 64 + (wc ^ (((ml >> 2) & 3) << 3))];
            int n = n0 + wc * 2;
            int part = (n >= 1536) ? 2 : (n >= 768 ? 1 : 0);
            int rem = n - part * 768;
            int h = rem >> 6, d = rem & 63;
            int m = m0 + ml, b = m >> 10, t = m & 1023;
            short* dst = (part == 0 ? Qb : part == 1 ? Kb : Vb)
                         + (((size_t)b * NH + h) * TT + t) * HD + d;
            *(int4*)dst = dat;
        }
    } else {
#pragma unroll
        for (int mi = 0; mi < 4; mi++)
#pragma unroll
            for (int ni = 0; ni < 4; ni++) {
                int n = n0 + wn * 64 + ni * 16 + c;
                float bv = bias[n];
#pragma unroll
                for (int r = 0; r < 4; r++) {
                    int m = m0 + wm * 64 + mi * 16 + g * 4 + r;
                    out[(size_t)m * CC + n] = acc[mi][ni][r] + bv;
                }
            }
    }
#undef STAGE
}

// ---------------------------------------------------------------- flash attention
// (unchanged — passed 4x; swapped-operand S^T = mfma(K,Q), lane-local softmax,
// per-wave barrier-free LDS P-tile, V from global VT, LDS O^T epilogue)
__global__ __launch_bounds__(256)
void attn_kernel(const short* __restrict__ Qb, const short* __restrict__ Kb,
                 const short* __restrict__ VT, short* __restrict__ Ob) {
    __shared__ uint32_t Pt[4][32][32];  // 16 KB per-wave P tile, XOR-swizzled
    __shared__ uint32_t ot[128 * 32];   // 16 KB epilogue O^T transpose
    const int tid = threadIdx.x, lane = tid & 63, wid = tid >> 6;
    const int g = lane >> 4, c = lane & 15;
    const int bh = blockIdx.x, qb = 7 - (int)blockIdx.y;
    const int b = bh / NH, h = bh % NH;
    const short* Qp = Qb + (size_t)bh * TT * HD;
    const short* Kp = Kb + (size_t)bh * TT * HD;
    const short* Vp = VT + (size_t)bh * TT * HD;
    const int q0 = qb * 128 + wid * 32;
    const int sw = (c & 7) << 2;

    bf16x8 qf[2][2];
#pragma unroll
    for (int qs = 0; qs < 2; qs++)
#pragma unroll
        for (int kh = 0; kh < 2; kh++)
            qf[qs][kh] = *(const bf16x8*)(Qp + (size_t)(q0 + qs * 16 + c) * HD + kh * 32 + g * 8);

    const f32x4 zero4 = {0.f, 0.f, 0.f, 0.f};
    f32x4 o[2][4];
#pragma unroll
    for (int qs = 0; qs < 2; qs++)
#pragma unroll
        for (int dt = 0; dt < 4; dt++) o[qs][dt] = zero4;
    float mrun[2] = {-1e30f, -1e30f}, lrun[2] = {0.f, 0.f};

    const int t0max = ((q0 + 31) >> 6) << 6;
    for (int t0 = 0; t0 <= t0max; t0 += 64) {
        f32x4 st[2][4];
#pragma unroll
        for (int nt = 0; nt < 4; nt++) {
            const short* kp = Kp + (size_t)(t0 + nt * 16 + c) * HD + g * 8;
            bf16x8 k0 = *(const bf16x8*)kp;
            bf16x8 k1 = *(const bf16x8*)(kp + 32);
#pragma unroll
            for (int qs = 0; qs < 2; qs++) {
                f32x4 z = zero4;
                z = __builtin_amdgcn_mfma_f32_16x16x32_bf16(k0, qf[qs][0], z, 0, 0, 0);
                z = __builtin_amdgcn_mfma_f32_16x16x32_bf16(k1, qf[qs][1], z, 0, 0, 0);
                st[qs][nt] = z;
            }
        }
        bf16x8 vf[2][4];
#pragma unroll
        for (int blk = 0; blk < 2; blk++)
#pragma unroll
            for (int dt = 0; dt < 4; dt++)
                vf[blk][dt] = *(const bf16x8*)(Vp + (size_t)(dt * 16 + c) * TT + t0 + blk * 32 + g * 8);
        if (t0 + 63 > q0) {
#pragma unroll
            for (int qs = 0; qs < 2; qs++) {
                int q = q0 + qs * 16 + c;
#pragma unroll
                for (int nt = 0; nt < 4; nt++)
#pragma unroll
                    for (int r = 0; r < 4; r++)
                        if (t0 + nt * 16 + g * 4 + r > q) st[qs][nt][r] = -1e30f;
            }
        }
#pragma unroll
        for (int qs = 0; qs < 2; qs++) {
            float mx = st[qs][0][0];
#pragma unroll
            for (int nt = 0; nt < 4; nt++)
#pragma unroll
                for (int r = 0; r < 4; r++) mx = fmaxf(mx, st[qs][nt][r]);
            mx = fmaxf(mx, __shfl_xor(mx, 16));
            mx = fmaxf(mx, __shfl_xor(mx, 32));
            float mnew = fmaxf(mrun[qs], mx);
            float al = __expf(mrun[qs] - mnew);
            mrun[qs] = mnew;
            float sm = 0.f;
#pragma unroll
            for (int nt = 0; nt < 4; nt++)
#pragma unroll
                for (int r = 0; r < 4; r++) {
                    float e = __expf(st[qs][nt][r] - mnew);
                    st[qs][nt][r] = e;
                    sm += e;
                }
            sm += __shfl_xor(sm, 16);
            sm += __shfl_xor(sm, 32);
            lrun[qs] = lrun[qs] * al + sm;
#pragma unroll
            for (int dt = 0; dt < 4; dt++) {
                o[qs][dt][0] *= al; o[qs][dt][1] *= al;
                o[qs][dt][2] *= al; o[qs][dt][3] *= al;
            }
            int row = qs * 16 + c;
#pragma unroll
            for (int nt = 0; nt < 4; nt++) {
                uint32_t w0 = bfpack(st[qs][nt][0], st[qs][nt][1]);
                uint32_t w1 = bfpack(st[qs][nt][2], st[qs][nt][3]);
                int wa = nt * 8 + 2 * g;
                Pt[wid][row][wa ^ sw]       = w0;
                Pt[wid][row][(wa + 1) ^ sw] = w1;
            }
        }
#pragma unroll
        for (int qs = 0; qs < 2; qs++) {
            int row = qs * 16 + c;
#pragma unroll
            for (int blk = 0; blk < 2; blk++) {
                bf16x8 pf = *(const bf16x8*)&Pt[wid][row][(blk * 16 + 4 * g) ^ sw];
#pragma unroll
                for (int dt = 0; dt < 4; dt++)
                    o[qs][dt] = __builtin_amdgcn_mfma_f32_16x16x32_bf16(
                        vf[blk][dt], pf, o[qs][dt], 0, 0, 0);
            }
        }
    }

#pragma unroll
    for (int qs = 0; qs < 2; qs++) {
        float inv = 1.0f / lrun[qs];
        int ql = wid * 32 + qs * 16 + c;
#pragma unroll
        for (int dt = 0; dt < 4; dt++) {
            uint32_t w0 = bfpack(o[qs][dt][0] * inv, o[qs][dt][1] * inv);
            uint32_t w1 = bfpack(o[qs][dt][2] * inv, o[qs][dt][3] * inv);
            int jc0 = dt * 8 + 2 * g;
            int jc1 = jc0 + 1;
            ot[ql * 32 + ((((jc0 >> 2) ^ (c & 7)) << 2) | (jc0 & 3))] = w0;
            ot[ql * 32 + ((((jc1 >> 2) ^ (c & 7)) << 2) | (jc1 & 3))] = w1;
        }
    }
    __syncthreads();
#pragma unroll
    for (int p = 0; p < 4; p++) {
        int q = (tid >> 3) + 32 * p;
        int jb = tid & 7;
        const uint32_t* src = &ot[q * 32 + ((jb ^ (q & 7)) << 2)];
        int4 w = *(const int4*)src;
        *(int4*)(Ob + ((size_t)b * TT + qb * 128 + q) * CC + h * HD + jb * 8) = w;
    }
}

// ---------------------------------------------------------------- launch
extern "C" void kernel_launch(void* const* d_in, const int* in_sizes, int n_in,
                              void* d_out, int out_size, void* d_ws, size_t ws_size,
                              hipStream_t stream) {
    const float* x     = (const float*)d_in[0];
    const float* Wqkv  = (const float*)d_in[1];
    const float* bqkv  = (const float*)d_in[2];
    const float* Wproj = (const float*)d_in[3];
    const float* bproj = (const float*)d_in[4];
    // d_in[5] = mask: causal by construction, unused

    char* ws = (char*)d_ws;
    // ws layout: WqkvT 3538944 | WprojT 1179648 | fc 262144 | Qb | Kb | V/Ob | VbT
    // xb (bf16 x) ALIASES VbT: xb consumed by gemm1, VbT written later by vtrans.
    short*  WqkvT  = (short*)(ws);
    short*  WprojT = (short*)(ws + 3538944);
    float2* fc     = (float2*)(ws + 3538944 + 1179648);
    short*  Qb     = (short*)(ws + 4980736);
    short*  Kb     = (short*)(ws + 4980736 + 1 * 12582912);
    short*  VOb    = (short*)(ws + 4980736 + 2 * 12582912);  // V, then O after vtrans
    short*  VbT    = (short*)(ws + 4980736 + 3 * 12582912);
    short*  xb     = VbT;
    float*  out    = (float*)d_out;

    hipLaunchKernelGGL(fc_kernel, dim3(128), dim3(256), 0, stream, fc);
    hipLaunchKernelGGL(transpose_cast_kernel, dim3(72, 24), dim3(32, 8), 0, stream,
                       Wqkv, WqkvT, 768, 2304);
    hipLaunchKernelGGL(transpose_cast_kernel, dim3(24, 24), dim3(32, 8), 0, stream,
                       Wproj, WprojT, 768, 768);
    hipLaunchKernelGGL(cast_kernel, dim3(3072), dim3(256), 0, stream, x, xb);
    hipLaunchKernelGGL((gemm_kernel<0>), dim3(18, 64), dim3(256), 0, stream,
                       xb, WqkvT, bqkv, Qb, Kb, VOb, fc, (float*)nullptr);
    hipLaunchKernelGGL(vtrans_kernel, dim3(16, 96), dim3(256), 0, stream, VOb, VbT);
    hipLaunchKernelGGL(attn_kernel, dim3(96, 8), dim3(256), 0, stream, Qb, Kb, VbT, VOb);
    hipLaunchKernelGGL((gemm_kernel<1>), dim3(6, 64), dim3(256), 0, stream,
                       VOb, WprojT, bproj,
                       (short*)nullptr, (short*)nullptr, (short*)nullptr,
                       (const float2*)nullptr, out);
}